// Round 18
// baseline (101.430 us; speedup 1.0000x reference)
//
#include <hip/hip_runtime.h>
#include <hip/hip_bf16.h>

// Sizes for this problem instance
#define BB   2
#define SS   2048
#define HH   16
#define DM_  1024
#define DH_  64
#define NROW 4096   // BB*SS
#define NQKV 3072   // 3 * HH * DH

typedef unsigned short u16;
typedef unsigned int u32;
using short4v = __attribute__((ext_vector_type(4))) short;
using short8 = __attribute__((ext_vector_type(8))) short;
using bf16x8 = __attribute__((ext_vector_type(8))) __bf16;
using f32x4  = __attribute__((ext_vector_type(4))) float;
using f32x16 = __attribute__((ext_vector_type(16))) float;

// Q pre-scale: 1/sqrt(64) * 1/ln(2)  (so attention uses exp2 directly)
#define QSCALE 0.180336880f

__device__ __forceinline__ u16 f2bf(float f) {
    union { float f; unsigned u; } v; v.f = f;
    unsigned r = v.u + 0x7fffu + ((v.u >> 16) & 1u);
    return (u16)(r >> 16);
}

__device__ __forceinline__ f32x4 mfma16(bf16x8 a, bf16x8 b, f32x4 c) {
    return __builtin_amdgcn_mfma_f32_16x16x32_bf16(a, b, c, 0, 0, 0);
}
__device__ __forceinline__ f32x16 mfma32(bf16x8 a, bf16x8 b, f32x16 c) {
    return __builtin_amdgcn_mfma_f32_32x32x16_bf16(a, b, c, 0, 0, 0);
}

__device__ __forceinline__ u32 cvtpk(float lo, float hi) {
    u32 r;
    asm("v_cvt_pk_bf16_f32 %0, %1, %2" : "=v"(r) : "v"(lo), "v"(hi));
    return r;
}
#define PLSWAP(a, b) asm("v_permlane32_swap_b32 %0, %1" : "+v"(a), "+v"(b))

// raw v_exp_f32 (2^x) — avoids OCML denormal-fixup sequence
__device__ __forceinline__ float fexp2(float x) {
#if __has_builtin(__builtin_amdgcn_exp2f)
    return __builtin_amdgcn_exp2f(x);
#else
    float r; asm("v_exp_f32 %0, %1" : "=v"(r) : "v"(x)); return r;
#endif
}

// async global->LDS, 16B per lane (dest = wave-uniform base + lane*16)
__device__ __forceinline__ void gload16(const void* g, void* l) {
    __builtin_amdgcn_global_load_lds(
        (const __attribute__((address_space(1))) void*)g,
        (__attribute__((address_space(3))) void*)l, 16, 0, 0);
}

// ---------------------------------------------------------------------------
// prep: fused pack_x (vectorized) + trans_w + trans_wo + bias pack
// ---------------------------------------------------------------------------
__global__ __launch_bounds__(256)
void prep(const float* __restrict__ x,  const float* __restrict__ wq,
          const float* __restrict__ wk, const float* __restrict__ wv,
          const float* __restrict__ wo, const float* __restrict__ bq,
          const float* __restrict__ bk, const float* __restrict__ bv,
          u16* __restrict__ Xb, u16* __restrict__ Wt,
          u16* __restrict__ WoT, float* __restrict__ biasQKV) {
    __shared__ float tile[64][65];
    const int bx = blockIdx.x, t = threadIdx.x;
    if (bx < 512) {
        const int tid = bx * 256 + t;
        #pragma unroll
        for (int it = 0; it < 8; ++it) {
            int i = tid + it * 131072;
            float4 v = ((const float4*)x)[i];
            u16 b4[4] = {f2bf(v.x), f2bf(v.y), f2bf(v.z), f2bf(v.w)};
            ((short4v*)Xb)[i] = *(short4v*)b4;
        }
        if (tid < NQKV) {
            int mat = tid >> 10, h = (tid >> 6) & 15, d = tid & 63;
            const float* bb = (mat == 0) ? bq : ((mat == 1) ? bk : bv);
            biasQKV[tid] = bb[h * DH_ + d];
        }
    } else if (bx < 1280) {
        const int idx = bx - 512;
        const int m0 = (idx & 15) * 64, hm = idx >> 4;
        const int mat = hm >> 4, h = hm & 15;
        const float* w = (mat == 0) ? wq : ((mat == 1) ? wk : wv);
        #pragma unroll
        for (int it = 0; it < 4; ++it) {
            int row = it * 16 + (t >> 4), c4 = (t & 15) * 4;
            float4 v = *(const float4*)&w[((size_t)h * 1024 + m0 + row) * 64 + c4];
            tile[row][c4] = v.x; tile[row][c4 + 1] = v.y;
            tile[row][c4 + 2] = v.z; tile[row][c4 + 3] = v.w;
        }
        __syncthreads();
        #pragma unroll
        for (int it = 0; it < 2; ++it) {
            int c = it * 256 + t, d = c >> 3, mc = (c & 7) * 8;
            u16 buf[8];
            #pragma unroll
            for (int j = 0; j < 8; ++j) buf[j] = f2bf(tile[mc + j][d]);
            *(short8*)&Wt[((size_t)(mat * 1024 + h * 64 + d)) * 1024 + m0 + mc] = *(short8*)buf;
        }
    } else {
        const int idx = bx - 1280;
        const int n0 = (idx & 15) * 64, k0 = (idx >> 4) * 64;
        #pragma unroll
        for (int it = 0; it < 4; ++it) {
            int row = it * 16 + (t >> 4), c4 = (t & 15) * 4;
            float4 v = *(const float4*)&wo[(size_t)(k0 + row) * DM_ + n0 + c4];
            tile[row][c4] = v.x; tile[row][c4 + 1] = v.y;
            tile[row][c4 + 2] = v.z; tile[row][c4 + 3] = v.w;
        }
        __syncthreads();
        #pragma unroll
        for (int it = 0; it < 2; ++it) {
            int c = it * 256 + t, n = c >> 3, kc = (c & 7) * 8;
            u16 buf[8];
            #pragma unroll
            for (int j = 0; j < 8; ++j) buf[j] = f2bf(tile[kc + j][n]);
            *(short8*)&WoT[(size_t)(n0 + n) * DM_ + k0 + kc] = *(short8*)buf;
        }
    }
}

// ---------------------------------------------------------------------------
// gemm_core_128: pipelined 128x128-tile GEMM body (round-7 proven structure)
// ---------------------------------------------------------------------------
__device__ __forceinline__ void gemm_core_128(
    const u16* __restrict__ Ap, const u16* __restrict__ Bp,
    int brow, int bcol, u16* lds, f32x4 acc[4][2]) {
    const int t = threadIdx.x, l = t & 63;
    const int wid = t >> 6, wm = wid >> 2, wn = wid & 3;
    const int c0 = t, c1 = t + 512;
    const int r0 = c0 >> 3, sb0 = ((c0 & 7) ^ (r0 & 7)) << 3;
    const int r1 = c1 >> 3, sb1 = ((c1 & 7) ^ (r1 & 7)) << 3;
    u16* A0 = lds;
    u16* B0 = lds + 16384;
    const int rA0 = wm * 64 + (l & 15);
    const int rB0 = wn * 32 + (l & 15);
    const int sw  = (l & 7) << 3;
    const int colA = ((l >> 4) << 3);

    {
        gload16(Ap + (size_t)(brow + r0) * DM_ + sb0, A0 + c0 * 8);
        gload16(Ap + (size_t)(brow + r1) * DM_ + sb1, A0 + c1 * 8);
        gload16(Bp + (size_t)(bcol + r0) * DM_ + sb0, B0 + c0 * 8);
        gload16(Bp + (size_t)(bcol + r1) * DM_ + sb1, B0 + c1 * 8);
    }
    __syncthreads();
    for (int kt = 0; kt < 16; ++kt) {
        const int p = kt & 1;
        if (kt < 15) {
            const int ko = (kt + 1) * 64;
            gload16(Ap + (size_t)(brow + r0) * DM_ + ko + sb0, A0 + (p ^ 1) * 8192 + c0 * 8);
            gload16(Ap + (size_t)(brow + r1) * DM_ + ko + sb1, A0 + (p ^ 1) * 8192 + c1 * 8);
            gload16(Bp + (size_t)(bcol + r0) * DM_ + ko + sb0, B0 + (p ^ 1) * 8192 + c0 * 8);
            gload16(Bp + (size_t)(bcol + r1) * DM_ + ko + sb1, B0 + (p ^ 1) * 8192 + c1 * 8);
        }
        const u16* Ab = A0 + p * 8192;
        const u16* Bb = B0 + p * 8192;
        #pragma unroll
        for (int kc = 0; kc < 64; kc += 32) {
            const int cx = (kc + colA) ^ sw;
            bf16x8 af[4], bfr[2];
            #pragma unroll
            for (int m = 0; m < 4; ++m)
                af[m] = *(const bf16x8*)(Ab + (rA0 + m * 16) * 64 + cx);
            #pragma unroll
            for (int n = 0; n < 2; ++n)
                bfr[n] = *(const bf16x8*)(Bb + (rB0 + n * 16) * 64 + cx);
            __builtin_amdgcn_s_setprio(1);
            #pragma unroll
            for (int m = 0; m < 4; ++m)
                #pragma unroll
                for (int n = 0; n < 2; ++n)
                    acc[m][n] = mfma16(af[m], bfr[n], acc[m][n]);
            __builtin_amdgcn_s_setprio(0);
        }
        __syncthreads();
    }
}

// ---------------------------------------------------------------------------
// gemm_qkv3: blocks 0..511: [4096,1024]@[1024,2048] -> Q(scaled), K
//            blocks 512..767: Vt = WtV @ Xb^T -> Vt[b*1024+n'][s]
// ---------------------------------------------------------------------------
__global__ __launch_bounds__(512)
void gemm_qkv3(const u16* __restrict__ Xb, const u16* __restrict__ Wt,
               const float* __restrict__ bias, u16* __restrict__ Qs,
               u16* __restrict__ Ks, u16* __restrict__ Vt) {
    __shared__ __align__(16) u16 lds[32768];
    const int bx = blockIdx.x, t = threadIdx.x, l = t & 63;
    const int wid = t >> 6, wm = wid >> 2, wn = wid & 3;
    f32x4 acc[4][2] = {};
    const bool isV = (bx >= 512);
    int brow, bcol; const u16 *Ap, *Bp;
    if (!isV) { brow = (bx & 31) * 128; bcol = (bx >> 5) * 128; Ap = Xb; Bp = Wt; }
    else { int i2 = bx - 512; brow = (i2 & 7) * 128; bcol = (i2 >> 3) * 128;
           Ap = Wt + (size_t)2048 * DM_; Bp = Xb; }
    gemm_core_128(Ap, Bp, brow, bcol, lds, acc);

    u16* wr_ = lds + wid * 2048;
    const int colbase = bcol + wn * 32;
    const int rowbase = brow + wm * 64;
    const int rsub = ((l >> 4) << 2);
    if (!isV) {
        const float b0 = bias[colbase + (l & 15)];
        const float b1 = bias[colbase + 16 + (l & 15)];
        const float scl = (colbase < 1024) ? QSCALE : 1.0f;
        #pragma unroll
        for (int m = 0; m < 4; ++m)
            #pragma unroll
            for (int n = 0; n < 2; ++n) {
                const float bb = n ? b1 : b0;
                #pragma unroll
                for (int r = 0; r < 4; ++r)
                    wr_[(m * 16 + rsub + r) * 32 + n * 16 + (l & 15)] =
                        f2bf((acc[m][n][r] + bb) * scl);
            }
    } else {
        #pragma unroll
        for (int m = 0; m < 4; ++m) {
            float4 bv = *(const float4*)&bias[2048 + rowbase + m * 16 + rsub];
            const float bbr[4] = {bv.x, bv.y, bv.z, bv.w};
            #pragma unroll
            for (int n = 0; n < 2; ++n)
                #pragma unroll
                for (int r = 0; r < 4; ++r)
                    wr_[(m * 16 + rsub + r) * 32 + n * 16 + (l & 15)] =
                        f2bf(acc[m][n][r] + bbr[r]);
        }
    }
    __syncthreads();
    if (!isV) {
        const int hsel = (colbase >> 6) & 15, d0 = colbase & 63;
        const int bsel = rowbase >> 11, s0 = rowbase & 2047;
        u16* outp = (colbase < 1024) ? Qs : Ks;
        #pragma unroll
        for (int p = 0; p < 4; ++p) {
            const int rr = p * 16 + (l >> 2);
            short8 v = *(const short8*)(wr_ + rr * 32 + (l & 3) * 8);
            *(short8*)&outp[(((size_t)bsel * HH + hsel) * SS + s0 + rr) * DH_ + d0 + (l & 3) * 8] = v;
        }
    } else {
        const int bsel = colbase >> 11, s0 = colbase & 2047;
        #pragma unroll
        for (int p = 0; p < 4; ++p) {
            const int rr = p * 16 + (l >> 2);
            short8 v = *(const short8*)(wr_ + rr * 32 + (l & 3) * 8);
            *(short8*)&Vt[((size_t)bsel * 1024 + rowbase + rr) * SS + s0 + (l & 3) * 8] = v;
        }
    }
}

// ---------------------------------------------------------------------------
// gemm_out3: [4096,1024] @ [1024,1024] + b_O -> fp32 (round-7 version)
// ---------------------------------------------------------------------------
__global__ __launch_bounds__(512)
void gemm_out3(const u16* __restrict__ Zb, const u16* __restrict__ WoT,
               const float* __restrict__ bO, float* __restrict__ out) {
    __shared__ __align__(16) u16 lds[32768];
    const int bx = blockIdx.x, t = threadIdx.x, l = t & 63;
    const int wid = t >> 6, wm = wid >> 2, wn = wid & 3;
    const int brow = (bx & 31) * 128, bcol = (bx >> 5) * 128;
    f32x4 acc[4][2] = {};
    gemm_core_128(Zb, WoT, brow, bcol, lds, acc);
    const int colbase = bcol + wn * 32;
    const int rowbase = brow + wm * 64;
    const int rsub = ((l >> 4) << 2);
    const float b0 = bO[colbase + (l & 15)];
    const float b1 = bO[colbase + 16 + (l & 15)];
    #pragma unroll
    for (int m = 0; m < 4; ++m)
        #pragma unroll
        for (int n = 0; n < 2; ++n) {
            const float bb = n ? b1 : b0;
            #pragma unroll
            for (int r = 0; r < 4; ++r)
                out[(size_t)(rowbase + m * 16 + rsub + r) * DM_ + colbase + n * 16 + (l & 15)] =
                    acc[m][n][r] + bb;
        }
}

// ---------------------------------------------------------------------------
// attn: 64-q warps. 256-thread blocks, 4 warps = 2 qh(64 q) x 2 k-parity.
// QBLK=128, KVBLK=128/round, r12 async-dbuf global_load_lds staging (one
// barrier/round). Shared K/V fragments feed BOTH q-groups: 8 K + 8 V
// ds_read_b128 per round per warp for 64 q (vs 16 for 32 q) -> LDS-pipe
// traffic per CU halved; two independent q-group MFMA chains double ILP.
// 512 blocks (r12 {15-a, a} mapping); 2 blocks/CU = 2 waves/SIMD.
// Static-max softmax (exp2), exact parity sum-merge. No setprio.
// ---------------------------------------------------------------------------
__global__ __launch_bounds__(256, 2)
void attn_fwd(const u16* __restrict__ Qs, const u16* __restrict__ Ks,
              const u16* __restrict__ Vt, u16* __restrict__ Zb) {
    __shared__ __align__(16) u16 fK[2][8192];   // 32 KB: [buf][128 kseq x 64 d]
    __shared__ __align__(16) u16 fV[2][8192];   // 32 KB: [buf][64 d x 128 kseq]
    __shared__ float lrP[128];                  // [qh][qg][c32]
    __shared__ float lrX[128];
    const int bidx = blockIdx.x;
    const int j  = (bidx < 256) ? (15 - (bidx >> 5)) : ((bidx - 256) >> 5);
    const int bh = bidx & 31, b = bh >> 4, h = bh & 15;
    const int t = threadIdx.x, wid = t >> 6, l = t & 63;
    const int hi = l >> 5, c32 = l & 31;
    const int qh = wid >> 1, par = wid & 1;
    const u16* Qp = Qs + (size_t)bh * SS * DH_;
    const u16* Kp = Ks + (size_t)bh * SS * DH_;
    const u16* Vp = Vt + (size_t)bh * DH_ * SS;
    const int qw = j * 128 + qh * 64;        // warp's first q row (64 q)
    const int nr = j + 1;                    // 128-k rounds

    // Q B-fragments, both q-groups
    bf16x8 aq0[4], aq1[4];
    #pragma unroll
    for (int dk = 0; dk < 4; ++dk) {
        aq0[dk] = *(const bf16x8*)&Qp[(size_t)(qw + c32) * DH_ + dk * 16 + hi * 8];
        aq1[dk] = *(const bf16x8*)&Qp[(size_t)(qw + 32 + c32) * DH_ + dk * 16 + hi * 8];
    }

    // staging chunks: thread t owns chunks c = t + 256*i, i = 0..3
    int kOff[4]; size_t vOff[4]; int dstc[4];
    #pragma unroll
    for (int i = 0; i < 4; ++i) {
        const int c = t + 256 * i, sec = c >> 6, ln = c & 63;
        const int kh = sec >> 3, s7 = sec & 7;
        kOff[i] = (kh * 64 + (s7 >> 2) * 32 + (ln & 31)) * DH_ + (s7 & 3) * 16 + (ln >> 5) * 8;
        vOff[i] = (size_t)((s7 >> 2) * 32 + (ln & 31)) * SS + kh * 64 + (s7 & 3) * 16 + (ln >> 5) * 8;
        dstc[i] = c * 8;
    }

    #define ISSUE(rr, pb)                                                     \
    {   const int ka = (rr) * 128;                                            \
        gload16(Kp + (size_t)ka * DH_ + kOff[0], &fK[pb][dstc[0]]);           \
        gload16(Kp + (size_t)ka * DH_ + kOff[1], &fK[pb][dstc[1]]);           \
        gload16(Kp + (size_t)ka * DH_ + kOff[2], &fK[pb][dstc[2]]);           \
        gload16(Kp + (size_t)ka * DH_ + kOff[3], &fK[pb][dstc[3]]);           \
        gload16(Vp + ka + vOff[0], &fV[pb][dstc[0]]);                         \
        gload16(Vp + ka + vOff[1], &fV[pb][dstc[1]]);                         \
        gload16(Vp + ka + vOff[2], &fV[pb][dstc[2]]);                         \
        gload16(Vp + ka + vOff[3], &fV[pb][dstc[3]]);                         \
    }

    // prologue: issue round 0 into buf 0, drain
    ISSUE(0, 0)
    __syncthreads();

    f32x16 o00 = {}, o01 = {}, o10 = {}, o11 = {};   // [qg][dhalf]
    float lrp0[4] = {0.f, 0.f, 0.f, 0.f};
    float lrp1[4] = {0.f, 0.f, 0.f, 0.f};

    for (int r = 0; r < nr; ++r) {
        const int p = r & 1;
        if (r + 1 < nr) ISSUE(r + 1, p ^ 1)   // flies under this round's compute
        const int kv0 = r * 128 + par * 64;   // this warp's 64-k tile
        if (kv0 <= qw + 63) {
            const u16* fKb = &fK[p][par * 4096];
            const u16* fVb = &fV[p][par * 4096];
            #pragma unroll
            for (int kg = 0; kg < 2; ++kg) {
                const int kb = kv0 + kg * 32;
                if (kb > qw + 63) continue;           // fully masked for both qg
                const bool nd0 = (kb <= qw + 31);     // qg0 needs this k-group
                f32x16 sA = {}, sB = {};
                #pragma unroll
                for (int dk = 0; dk < 4; ++dk) {
                    bf16x8 kf = *(const bf16x8*)(fKb + (kg * 4 + dk) * 512 + l * 8);
                    if (nd0) sA = mfma32(kf, aq0[dk], sA);
                    sB = mfma32(kf, aq1[dk], sB);
                }
                // causal masks (wave-uniform conditions)
                if (nd0 && kb + 31 > qw) {
                    const int q = qw + c32;
                    #pragma unroll
                    for (int r16 = 0; r16 < 16; ++r16) {
                        const int crow = (r16 & 3) + 8 * (r16 >> 2) + 4 * hi;
                        if (kb + crow > q) sA[r16] = -1e30f;
                    }
                }
                if (kb + 31 > qw + 32) {
                    const int q = qw + 32 + c32;
                    #pragma unroll
                    for (int r16 = 0; r16 < 16; ++r16) {
                        const int crow = (r16 & 3) + 8 * (r16 >> 2) + 4 * hi;
                        if (kb + crow > q) sB[r16] = -1e30f;
                    }
                }
                // p = exp2(s); per-lane partial sums
                if (nd0) {
                    #pragma unroll
                    for (int r16 = 0; r16 < 16; ++r16) {
                        sA[r16] = fexp2(sA[r16]);
                        lrp0[r16 & 3] += sA[r16];
                    }
                }
                #pragma unroll
                for (int r16 = 0; r16 < 16; ++r16) {
                    sB[r16] = fexp2(sB[r16]);
                    lrp1[r16 & 3] += sB[r16];
                }
                // PV: 2 k-steps; V fragments shared across q-groups
                #pragma unroll
                for (int h8 = 0; h8 < 2; ++h8) {
                    const int KS = kg * 2 + h8;
                    const int B8 = h8 * 8;
                    bf16x8 v0 = *(const bf16x8*)(fVb + (0 * 4 + KS) * 512 + l * 8);
                    bf16x8 v1 = *(const bf16x8*)(fVb + (1 * 4 + KS) * 512 + l * 8);
                    if (nd0) {
                        u32 cA  = cvtpk(sA[B8 + 0], sA[B8 + 1]);
                        u32 cA2 = cvtpk(sA[B8 + 2], sA[B8 + 3]);
                        u32 cB  = cvtpk(sA[B8 + 4], sA[B8 + 5]);
                        u32 cB2 = cvtpk(sA[B8 + 6], sA[B8 + 7]);
                        PLSWAP(cA, cB); PLSWAP(cA2, cB2);
                        u32 w0[4] = {cA, cA2, cB, cB2};
                        bf16x8 pa = *(bf16x8*)w0;
                        o00 = mfma32(pa, v0, o00);
                        o01 = mfma32(pa, v1, o01);
                    }
                    {
                        u32 cA  = cvtpk(sB[B8 + 0], sB[B8 + 1]);
                        u32 cA2 = cvtpk(sB[B8 + 2], sB[B8 + 3]);
                        u32 cB  = cvtpk(sB[B8 + 4], sB[B8 + 5]);
                        u32 cB2 = cvtpk(sB[B8 + 6], sB[B8 + 7]);
                        PLSWAP(cA, cB); PLSWAP(cA2, cB2);
                        u32 w1[4] = {cA, cA2, cB, cB2};
                        bf16x8 pa = *(bf16x8*)w1;
                        o10 = mfma32(pa, v0, o10);
                        o11 = mfma32(pa, v1, o11);
                    }
                }
            }
        }
        __syncthreads();   // releases buf p readers + lands round r+1 loads
    }
    #undef ISSUE

    float lrow0 = (lrp0[0] + lrp0[1]) + (lrp0[2] + lrp0[3]);
    float lrow1 = (lrp1[0] + lrp1[1]) + (lrp1[2] + lrp1[3]);
    lrow0 += __shfl_xor(lrow0, 32);          // combine hi halves (this parity)
    lrow1 += __shfl_xor(lrow1, 32);

    // ---- merge parity pairs: o_tot = o_even + o_odd, l_tot = sum (static max)
    float* mrg = (float*)fK;                 // 32 KB = 4 (qh,qg) x 2048 floats
    __syncthreads();                          // all compute done before overwrite
    const int rg0 = (qh * 2 + 0) * 2048, rg1 = (qh * 2 + 1) * 2048;
    if (par) {
        #pragma unroll
        for (int e = 0; e < 16; ++e) mrg[rg0 + e * 64 + l] = o00[e];
        #pragma unroll
        for (int e = 0; e < 16; ++e) mrg[rg0 + (16 + e) * 64 + l] = o01[e];
        #pragma unroll
        for (int e = 0; e < 16; ++e) mrg[rg1 + e * 64 + l] = o10[e];
        #pragma unroll
        for (int e = 0; e < 16; ++e) mrg[rg1 + (16 + e) * 64 + l] = o11[e];
        if (hi == 0) {
            lrP[(qh * 2 + 0) * 32 + c32] = lrow0;
            lrP[(qh * 2 + 1) * 32 + c32] = lrow1;
        }
    }
    __syncthreads();
    if (!par) {
        #pragma unroll
        for (int e = 0; e < 16; ++e) o00[e] += mrg[rg0 + e * 64 + l];
        #pragma unroll
        for (int e = 0; e < 16; ++e) o01[e] += mrg[rg0 + (16 + e) * 64 + l];
        #pragma unroll
        for (int e = 0; e < 16; ++e) o10[e] += mrg[rg1 + e * 64 + l];
        #pragma unroll
        for (int e = 0; e < 16; ++e) o11[e] += mrg[rg1 + (16 + e) * 64 + l];
        lrow0 += lrP[(qh * 2 + 0) * 32 + c32];
        lrow1 += lrP[(qh * 2 + 1) * 32 + c32];
        lrX[(qh * 2 + 0) * 32 + c32] = lrow0;
        lrX[(qh * 2 + 1) * 32 + c32] = lrow1;
        float inv0[16], inv1[16];
        #pragma unroll
        for (int g = 0; g < 4; ++g) {
            float4 lv0 = *(const float4*)&lrX[(qh * 2 + 0) * 32 + 8 * g + 4 * hi];
            float4 lv1 = *(const float4*)&lrX[(qh * 2 + 1) * 32 + 8 * g + 4 * hi];
            inv0[g * 4 + 0] = 1.0f / lv0.x; inv0[g * 4 + 1] = 1.0f / lv0.y;
            inv0[g * 4 + 2] = 1.0f / lv0.z; inv0[g * 4 + 3] = 1.0f / lv0.w;
            inv1[g * 4 + 0] = 1.0f / lv1.x; inv1[g * 4 + 1] = 1.0f / lv1.y;
            inv1[g * 4 + 2] = 1.0f / lv1.z; inv1[g * 4 + 3] = 1.0f / lv1.w;
        }
        #pragma unroll
        for (int r16 = 0; r16 < 16; ++r16) {
            const int crow = (r16 & 3) + 8 * (r16 >> 2) + 4 * hi;
            u16* zp0 = &Zb[(((size_t)b * SS + (qw + crow)) * HH + h) * DH_];
            u16* zp1 = &Zb[(((size_t)b * SS + (qw + 32 + crow)) * HH + h) * DH_];
            zp0[c32]      = f2bf(o00[r16] * inv0[r16]);
            zp0[32 + c32] = f2bf(o01[r16] * inv0[r16]);
            zp1[c32]      = f2bf(o10[r16] * inv1[r16]);
            zp1[32 + c32] = f2bf(o11[r16] * inv1[r16]);
        }
    }
}

// ---------------------------------------------------------------------------
extern "C" void kernel_launch(void* const* d_in, const int* in_sizes, int n_in,
                              void* d_out, int out_size, void* d_ws, size_t ws_size,
                              hipStream_t stream) {
    const float* x  = (const float*)d_in[0];
    const float* wq = (const float*)d_in[1];
    const float* wk = (const float*)d_in[2];
    const float* wv = (const float*)d_in[3];
    const float* wo = (const float*)d_in[4];
    const float* bq = (const float*)d_in[5];
    const float* bk = (const float*)d_in[6];
    const float* bv = (const float*)d_in[7];
    const float* bO = (const float*)d_in[8];
    float* out = (float*)d_out;

    char* w = (char*)d_ws;
    u16* Xb  = (u16*)w;  w += (size_t)NROW * DM_ * 2;
    u16* Wt  = (u16*)w;  w += (size_t)NQKV * DM_ * 2;
    u16* WoT = (u16*)w;  w += (size_t)DM_ * DM_ * 2;
    float* biasQKV = (float*)w; w += (size_t)NQKV * 4;
    u16* Qs  = (u16*)w;  w += (size_t)BB * HH * SS * DH_ * 2;
    u16* Ks  = (u16*)w;  w += (size_t)BB * HH * SS * DH_ * 2;
    u16* Vt  = (u16*)w;  w += (size_t)BB * HH * SS * DH_ * 2;
    u16* Zb  = (u16*)w;  w += (size_t)BB * HH * SS * DH_ * 2;

    prep<<<1536, 256, 0, stream>>>(x, wq, wk, wv, wo, bq, bk, bv,
                                   Xb, Wt, WoT, biasQKV);
    gemm_qkv3<<<768, 512, 0, stream>>>(Xb, Wt, biasQKV, Qs, Ks, Vt);
    attn_fwd<<<512, 256, 0, stream>>>(Qs, Ks, Vt, Zb);
    gemm_out3<<<256, 512, 0, stream>>>(Zb, WoT, bO, out);
}

// Round 19
// 94.712 us; speedup vs baseline: 1.0709x; 1.0709x over previous
//
#include <hip/hip_runtime.h>
#include <hip/hip_bf16.h>

// Sizes for this problem instance
#define BB   2
#define SS   2048
#define HH   16
#define DM_  1024
#define DH_  64
#define NROW 4096   // BB*SS
#define NQKV 3072   // 3 * HH * DH

typedef unsigned short u16;
typedef unsigned int u32;
using short4v = __attribute__((ext_vector_type(4))) short;
using short8 = __attribute__((ext_vector_type(8))) short;
using bf16x8 = __attribute__((ext_vector_type(8))) __bf16;
using f32x4  = __attribute__((ext_vector_type(4))) float;
using f32x16 = __attribute__((ext_vector_type(16))) float;

// Q pre-scale: 1/sqrt(64) * 1/ln(2)  (so attention uses exp2 directly)
#define QSCALE 0.180336880f

__device__ __forceinline__ u16 f2bf(float f) {
    union { float f; unsigned u; } v; v.f = f;
    unsigned r = v.u + 0x7fffu + ((v.u >> 16) & 1u);
    return (u16)(r >> 16);
}

__device__ __forceinline__ f32x4 mfma16(bf16x8 a, bf16x8 b, f32x4 c) {
    return __builtin_amdgcn_mfma_f32_16x16x32_bf16(a, b, c, 0, 0, 0);
}
__device__ __forceinline__ f32x16 mfma32(bf16x8 a, bf16x8 b, f32x16 c) {
    return __builtin_amdgcn_mfma_f32_32x32x16_bf16(a, b, c, 0, 0, 0);
}

__device__ __forceinline__ u32 cvtpk(float lo, float hi) {
    u32 r;
    asm("v_cvt_pk_bf16_f32 %0, %1, %2" : "=v"(r) : "v"(lo), "v"(hi));
    return r;
}
#define PLSWAP(a, b) asm("v_permlane32_swap_b32 %0, %1" : "+v"(a), "+v"(b))

// raw v_exp_f32 (2^x) — avoids OCML denormal-fixup sequence
__device__ __forceinline__ float fexp2(float x) {
#if __has_builtin(__builtin_amdgcn_exp2f)
    return __builtin_amdgcn_exp2f(x);
#else
    float r; asm("v_exp_f32 %0, %1" : "=v"(r) : "v"(x)); return r;
#endif
}

// async global->LDS, 16B per lane (dest = wave-uniform base + lane*16)
__device__ __forceinline__ void gload16(const void* g, void* l) {
    __builtin_amdgcn_global_load_lds(
        (const __attribute__((address_space(1))) void*)g,
        (__attribute__((address_space(3))) void*)l, 16, 0, 0);
}

// ---------------------------------------------------------------------------
// prep: fused pack_x (vectorized) + trans_w + trans_wo + bias pack
// ---------------------------------------------------------------------------
__global__ __launch_bounds__(256)
void prep(const float* __restrict__ x,  const float* __restrict__ wq,
          const float* __restrict__ wk, const float* __restrict__ wv,
          const float* __restrict__ wo, const float* __restrict__ bq,
          const float* __restrict__ bk, const float* __restrict__ bv,
          u16* __restrict__ Xb, u16* __restrict__ Wt,
          u16* __restrict__ WoT, float* __restrict__ biasQKV) {
    __shared__ float tile[64][65];
    const int bx = blockIdx.x, t = threadIdx.x;
    if (bx < 512) {
        const int tid = bx * 256 + t;
        #pragma unroll
        for (int it = 0; it < 8; ++it) {
            int i = tid + it * 131072;
            float4 v = ((const float4*)x)[i];
            u16 b4[4] = {f2bf(v.x), f2bf(v.y), f2bf(v.z), f2bf(v.w)};
            ((short4v*)Xb)[i] = *(short4v*)b4;
        }
        if (tid < NQKV) {
            int mat = tid >> 10, h = (tid >> 6) & 15, d = tid & 63;
            const float* bb = (mat == 0) ? bq : ((mat == 1) ? bk : bv);
            biasQKV[tid] = bb[h * DH_ + d];
        }
    } else if (bx < 1280) {
        const int idx = bx - 512;
        const int m0 = (idx & 15) * 64, hm = idx >> 4;
        const int mat = hm >> 4, h = hm & 15;
        const float* w = (mat == 0) ? wq : ((mat == 1) ? wk : wv);
        #pragma unroll
        for (int it = 0; it < 4; ++it) {
            int row = it * 16 + (t >> 4), c4 = (t & 15) * 4;
            float4 v = *(const float4*)&w[((size_t)h * 1024 + m0 + row) * 64 + c4];
            tile[row][c4] = v.x; tile[row][c4 + 1] = v.y;
            tile[row][c4 + 2] = v.z; tile[row][c4 + 3] = v.w;
        }
        __syncthreads();
        #pragma unroll
        for (int it = 0; it < 2; ++it) {
            int c = it * 256 + t, d = c >> 3, mc = (c & 7) * 8;
            u16 buf[8];
            #pragma unroll
            for (int j = 0; j < 8; ++j) buf[j] = f2bf(tile[mc + j][d]);
            *(short8*)&Wt[((size_t)(mat * 1024 + h * 64 + d)) * 1024 + m0 + mc] = *(short8*)buf;
        }
    } else {
        const int idx = bx - 1280;
        const int n0 = (idx & 15) * 64, k0 = (idx >> 4) * 64;
        #pragma unroll
        for (int it = 0; it < 4; ++it) {
            int row = it * 16 + (t >> 4), c4 = (t & 15) * 4;
            float4 v = *(const float4*)&wo[(size_t)(k0 + row) * DM_ + n0 + c4];
            tile[row][c4] = v.x; tile[row][c4 + 1] = v.y;
            tile[row][c4 + 2] = v.z; tile[row][c4 + 3] = v.w;
        }
        __syncthreads();
        #pragma unroll
        for (int it = 0; it < 2; ++it) {
            int c = it * 256 + t, n = c >> 3, kc = (c & 7) * 8;
            u16 buf[8];
            #pragma unroll
            for (int j = 0; j < 8; ++j) buf[j] = f2bf(tile[kc + j][n]);
            *(short8*)&WoT[(size_t)(n0 + n) * DM_ + k0 + kc] = *(short8*)buf;
        }
    }
}

// ---------------------------------------------------------------------------
// gemm_core_128: pipelined 128x128-tile GEMM body (round-7 proven structure)
// ---------------------------------------------------------------------------
__device__ __forceinline__ void gemm_core_128(
    const u16* __restrict__ Ap, const u16* __restrict__ Bp,
    int brow, int bcol, u16* lds, f32x4 acc[4][2]) {
    const int t = threadIdx.x, l = t & 63;
    const int wid = t >> 6, wm = wid >> 2, wn = wid & 3;
    const int c0 = t, c1 = t + 512;
    const int r0 = c0 >> 3, sb0 = ((c0 & 7) ^ (r0 & 7)) << 3;
    const int r1 = c1 >> 3, sb1 = ((c1 & 7) ^ (r1 & 7)) << 3;
    u16* A0 = lds;
    u16* B0 = lds + 16384;
    const int rA0 = wm * 64 + (l & 15);
    const int rB0 = wn * 32 + (l & 15);
    const int sw  = (l & 7) << 3;
    const int colA = ((l >> 4) << 3);

    {
        gload16(Ap + (size_t)(brow + r0) * DM_ + sb0, A0 + c0 * 8);
        gload16(Ap + (size_t)(brow + r1) * DM_ + sb1, A0 + c1 * 8);
        gload16(Bp + (size_t)(bcol + r0) * DM_ + sb0, B0 + c0 * 8);
        gload16(Bp + (size_t)(bcol + r1) * DM_ + sb1, B0 + c1 * 8);
    }
    __syncthreads();
    for (int kt = 0; kt < 16; ++kt) {
        const int p = kt & 1;
        if (kt < 15) {
            const int ko = (kt + 1) * 64;
            gload16(Ap + (size_t)(brow + r0) * DM_ + ko + sb0, A0 + (p ^ 1) * 8192 + c0 * 8);
            gload16(Ap + (size_t)(brow + r1) * DM_ + ko + sb1, A0 + (p ^ 1) * 8192 + c1 * 8);
            gload16(Bp + (size_t)(bcol + r0) * DM_ + ko + sb0, B0 + (p ^ 1) * 8192 + c0 * 8);
            gload16(Bp + (size_t)(bcol + r1) * DM_ + ko + sb1, B0 + (p ^ 1) * 8192 + c1 * 8);
        }
        const u16* Ab = A0 + p * 8192;
        const u16* Bb = B0 + p * 8192;
        #pragma unroll
        for (int kc = 0; kc < 64; kc += 32) {
            const int cx = (kc + colA) ^ sw;
            bf16x8 af[4], bfr[2];
            #pragma unroll
            for (int m = 0; m < 4; ++m)
                af[m] = *(const bf16x8*)(Ab + (rA0 + m * 16) * 64 + cx);
            #pragma unroll
            for (int n = 0; n < 2; ++n)
                bfr[n] = *(const bf16x8*)(Bb + (rB0 + n * 16) * 64 + cx);
            __builtin_amdgcn_s_setprio(1);
            #pragma unroll
            for (int m = 0; m < 4; ++m)
                #pragma unroll
                for (int n = 0; n < 2; ++n)
                    acc[m][n] = mfma16(af[m], bfr[n], acc[m][n]);
            __builtin_amdgcn_s_setprio(0);
        }
        __syncthreads();
    }
}

// ---------------------------------------------------------------------------
// gemm_qkv3: blocks 0..511: [4096,1024]@[1024,2048] -> Q(scaled), K
//            blocks 512..767: Vt = WtV @ Xb^T -> Vt[b*1024+n'][s]
// ---------------------------------------------------------------------------
__global__ __launch_bounds__(512)
void gemm_qkv3(const u16* __restrict__ Xb, const u16* __restrict__ Wt,
               const float* __restrict__ bias, u16* __restrict__ Qs,
               u16* __restrict__ Ks, u16* __restrict__ Vt) {
    __shared__ __align__(16) u16 lds[32768];
    const int bx = blockIdx.x, t = threadIdx.x, l = t & 63;
    const int wid = t >> 6, wm = wid >> 2, wn = wid & 3;
    f32x4 acc[4][2] = {};
    const bool isV = (bx >= 512);
    int brow, bcol; const u16 *Ap, *Bp;
    if (!isV) { brow = (bx & 31) * 128; bcol = (bx >> 5) * 128; Ap = Xb; Bp = Wt; }
    else { int i2 = bx - 512; brow = (i2 & 7) * 128; bcol = (i2 >> 3) * 128;
           Ap = Wt + (size_t)2048 * DM_; Bp = Xb; }
    gemm_core_128(Ap, Bp, brow, bcol, lds, acc);

    u16* wr_ = lds + wid * 2048;
    const int colbase = bcol + wn * 32;
    const int rowbase = brow + wm * 64;
    const int rsub = ((l >> 4) << 2);
    if (!isV) {
        const float b0 = bias[colbase + (l & 15)];
        const float b1 = bias[colbase + 16 + (l & 15)];
        const float scl = (colbase < 1024) ? QSCALE : 1.0f;
        #pragma unroll
        for (int m = 0; m < 4; ++m)
            #pragma unroll
            for (int n = 0; n < 2; ++n) {
                const float bb = n ? b1 : b0;
                #pragma unroll
                for (int r = 0; r < 4; ++r)
                    wr_[(m * 16 + rsub + r) * 32 + n * 16 + (l & 15)] =
                        f2bf((acc[m][n][r] + bb) * scl);
            }
    } else {
        #pragma unroll
        for (int m = 0; m < 4; ++m) {
            float4 bv = *(const float4*)&bias[2048 + rowbase + m * 16 + rsub];
            const float bbr[4] = {bv.x, bv.y, bv.z, bv.w};
            #pragma unroll
            for (int n = 0; n < 2; ++n)
                #pragma unroll
                for (int r = 0; r < 4; ++r)
                    wr_[(m * 16 + rsub + r) * 32 + n * 16 + (l & 15)] =
                        f2bf(acc[m][n][r] + bbr[r]);
        }
    }
    __syncthreads();
    if (!isV) {
        const int hsel = (colbase >> 6) & 15, d0 = colbase & 63;
        const int bsel = rowbase >> 11, s0 = rowbase & 2047;
        u16* outp = (colbase < 1024) ? Qs : Ks;
        #pragma unroll
        for (int p = 0; p < 4; ++p) {
            const int rr = p * 16 + (l >> 2);
            short8 v = *(const short8*)(wr_ + rr * 32 + (l & 3) * 8);
            *(short8*)&outp[(((size_t)bsel * HH + hsel) * SS + s0 + rr) * DH_ + d0 + (l & 3) * 8] = v;
        }
    } else {
        const int bsel = colbase >> 11, s0 = colbase & 2047;
        #pragma unroll
        for (int p = 0; p < 4; ++p) {
            const int rr = p * 16 + (l >> 2);
            short8 v = *(const short8*)(wr_ + rr * 32 + (l & 3) * 8);
            *(short8*)&Vt[((size_t)bsel * 1024 + rowbase + rr) * SS + s0 + (l & 3) * 8] = v;
        }
    }
}

// ---------------------------------------------------------------------------
// gemm_out3: [4096,1024] @ [1024,1024] + b_O -> fp32 (round-7 version)
// ---------------------------------------------------------------------------
__global__ __launch_bounds__(512)
void gemm_out3(const u16* __restrict__ Zb, const u16* __restrict__ WoT,
               const float* __restrict__ bO, float* __restrict__ out) {
    __shared__ __align__(16) u16 lds[32768];
    const int bx = blockIdx.x, t = threadIdx.x, l = t & 63;
    const int wid = t >> 6, wm = wid >> 2, wn = wid & 3;
    const int brow = (bx & 31) * 128, bcol = (bx >> 5) * 128;
    f32x4 acc[4][2] = {};
    gemm_core_128(Zb, WoT, brow, bcol, lds, acc);
    const int colbase = bcol + wn * 32;
    const int rowbase = brow + wm * 64;
    const int rsub = ((l >> 4) << 2);
    const float b0 = bO[colbase + (l & 15)];
    const float b1 = bO[colbase + 16 + (l & 15)];
    #pragma unroll
    for (int m = 0; m < 4; ++m)
        #pragma unroll
        for (int n = 0; n < 2; ++n) {
            const float bb = n ? b1 : b0;
            #pragma unroll
            for (int r = 0; r < 4; ++r)
                out[(size_t)(rowbase + m * 16 + rsub + r) * DM_ + colbase + n * 16 + (l & 15)] =
                    acc[m][n][r] + bb;
        }
}

// ---------------------------------------------------------------------------
// attn: r12 structure (measured best). 512-thread blocks (8 warps = 4 qh x
// 2 k-parity), QBLK=128, KVBLK=128/round. Double-buffered global_load_lds
// staging: round r+1's loads issued at the START of round r into buf p^1,
// flying under the whole compute phase; single end-of-round barrier lands
// them. 512 blocks paired {15-a, a}; 2 blocks/CU x 8 warps = 4 waves/SIMD.
// Static-max softmax (exp2), exact parity sum-merge. No setprio (m190:
// null-to-negative in barrier-synced lockstep structures).
// ---------------------------------------------------------------------------
__global__ __launch_bounds__(512, 4)
void attn_fwd(const u16* __restrict__ Qs, const u16* __restrict__ Ks,
              const u16* __restrict__ Vt, u16* __restrict__ Zb) {
    __shared__ __align__(16) u16 fK[2][8192];   // 32 KB: [buf][128 kseq x 64 d]
    __shared__ __align__(16) u16 fV[2][8192];   // 32 KB: [buf][64 d x 128 kseq]
    __shared__ float lrP[128];
    __shared__ float lrX[128];
    const int bidx = blockIdx.x;
    const int j  = (bidx < 256) ? (15 - (bidx >> 5)) : ((bidx - 256) >> 5);
    const int bh = bidx & 31, b = bh >> 4, h = bh & 15;
    const int t = threadIdx.x, wid = t >> 6, l = t & 63;
    const int hi = l >> 5, c32 = l & 31;
    const int qh = wid >> 1, par = wid & 1;
    const u16* Qp = Qs + (size_t)bh * SS * DH_;
    const u16* Kp = Ks + (size_t)bh * SS * DH_;
    const u16* Vp = Vt + (size_t)bh * DH_ * SS;
    const int qw = j * 128 + qh * 32;        // warp's first q row
    const int nr = j + 1;                    // 128-k rounds

    // Q B-fragments
    bf16x8 aq[4];
    #pragma unroll
    for (int dk = 0; dk < 4; ++dk)
        aq[dk] = *(const bf16x8*)&Qp[(size_t)(qw + c32) * DH_ + dk * 16 + hi * 8];

    // staging chunks: thread t owns chunks c = t, t+512 of each of K,V
    int kOff[2]; size_t vOff[2]; int dstc[2];
    #pragma unroll
    for (int i = 0; i < 2; ++i) {
        const int c = t + 512 * i, sec = c >> 6, ln = c & 63;
        const int kh = sec >> 3, s7 = sec & 7;
        kOff[i] = (kh * 64 + (s7 >> 2) * 32 + (ln & 31)) * DH_ + (s7 & 3) * 16 + (ln >> 5) * 8;
        vOff[i] = (size_t)((s7 >> 2) * 32 + (ln & 31)) * SS + kh * 64 + (s7 & 3) * 16 + (ln >> 5) * 8;
        dstc[i] = c * 8;
    }

    #define ISSUE(rr, pb)                                                     \
    {   const int ka = (rr) * 128;                                            \
        gload16(Kp + (size_t)ka * DH_ + kOff[0], &fK[pb][dstc[0]]);           \
        gload16(Kp + (size_t)ka * DH_ + kOff[1], &fK[pb][dstc[1]]);           \
        gload16(Vp + ka + vOff[0], &fV[pb][dstc[0]]);                         \
        gload16(Vp + ka + vOff[1], &fV[pb][dstc[1]]);                         \
    }

    // prologue: issue round 0 into buf 0, drain
    ISSUE(0, 0)
    __syncthreads();

    f32x16 o0 = {}, o1 = {};
    float lrp[4] = {0.f, 0.f, 0.f, 0.f};

    for (int r = 0; r < nr; ++r) {
        const int p = r & 1;
        if (r + 1 < nr) ISSUE(r + 1, p ^ 1)   // flies under this round's compute
        const int kv0 = r * 128 + par * 64;   // this warp's 64-k tile
        if (kv0 <= qw + 31) {
            const u16* fKb = &fK[p][par * 4096];
            const u16* fVb = &fV[p][par * 4096];
            const bool have1 = (kv0 + 32 <= qw + 31);
            f32x16 s0 = {}, s1 = {};
            #pragma unroll
            for (int dk = 0; dk < 4; ++dk)
                s0 = mfma32(*(const bf16x8*)(fKb + dk * 512 + l * 8), aq[dk], s0);
            if (have1) {
                #pragma unroll
                for (int dk = 0; dk < 4; ++dk)
                    s1 = mfma32(*(const bf16x8*)(fKb + (4 + dk) * 512 + l * 8), aq[dk], s1);
            }
            if (kv0 + 63 > qw) {              // diagonal overlap: causal mask
                const int q = qw + c32;
                #pragma unroll
                for (int r16 = 0; r16 < 16; ++r16) {
                    const int crow = (r16 & 3) + 8 * (r16 >> 2) + 4 * hi;
                    if (kv0 + crow > q) s0[r16] = -1e30f;
                }
                if (have1) {
                    #pragma unroll
                    for (int r16 = 0; r16 < 16; ++r16) {
                        const int crow = (r16 & 3) + 8 * (r16 >> 2) + 4 * hi;
                        if (kv0 + 32 + crow > q) s1[r16] = -1e30f;
                    }
                }
            }
            #pragma unroll
            for (int r16 = 0; r16 < 16; ++r16) {
                s0[r16] = fexp2(s0[r16]);
                lrp[r16 & 3] += s0[r16];
            }
            if (have1) {
                #pragma unroll
                for (int r16 = 0; r16 < 16; ++r16) {
                    s1[r16] = fexp2(s1[r16]);
                    lrp[r16 & 3] += s1[r16];
                }
            }
            #define PV_STEP(PS, B8, KS)                                          \
            {                                                                    \
                u32 cA  = cvtpk(PS[B8 + 0], PS[B8 + 1]);                         \
                u32 cA2 = cvtpk(PS[B8 + 2], PS[B8 + 3]);                         \
                u32 cB  = cvtpk(PS[B8 + 4], PS[B8 + 5]);                         \
                u32 cB2 = cvtpk(PS[B8 + 6], PS[B8 + 7]);                         \
                PLSWAP(cA, cB); PLSWAP(cA2, cB2);                                \
                u32 w[4] = {cA, cA2, cB, cB2};                                   \
                bf16x8 pa = *(bf16x8*)w;                                         \
                o0 = mfma32(pa, *(const bf16x8*)(fVb + (0 * 4 + (KS)) * 512 + l * 8), o0); \
                o1 = mfma32(pa, *(const bf16x8*)(fVb + (1 * 4 + (KS)) * 512 + l * 8), o1); \
            }
            PV_STEP(s0, 0, 0)
            PV_STEP(s0, 8, 1)
            if (have1) {
                PV_STEP(s1, 0, 2)
                PV_STEP(s1, 8, 3)
            }
            #undef PV_STEP
        }
        __syncthreads();   // releases buf p readers + lands round r+1 loads
    }
    #undef ISSUE

    float lrow = (lrp[0] + lrp[1]) + (lrp[2] + lrp[3]);
    lrow += __shfl_xor(lrow, 32);            // combine hi halves (this parity)

    // ---- merge parity pairs: o_tot = o_even + o_odd, l_tot = sum (static max)
    float* mrg = (float*)fK;                 // 32 KB = 4 qh x 2048 floats
    __syncthreads();                          // all compute done before overwrite
    if (par) {
        #pragma unroll
        for (int e = 0; e < 16; ++e) mrg[qh * 2048 + e * 64 + l] = o0[e];
        #pragma unroll
        for (int e = 0; e < 16; ++e) mrg[qh * 2048 + (16 + e) * 64 + l] = o1[e];
        if (hi == 0) lrP[qh * 32 + c32] = lrow;
    }
    __syncthreads();
    if (!par) {
        #pragma unroll
        for (int e = 0; e < 16; ++e) o0[e] += mrg[qh * 2048 + e * 64 + l];
        #pragma unroll
        for (int e = 0; e < 16; ++e) o1[e] += mrg[qh * 2048 + (16 + e) * 64 + l];
        lrow += lrP[qh * 32 + c32];
        lrX[qh * 32 + c32] = lrow;           // warp-local broadcast
        float invv[16];
        #pragma unroll
        for (int g = 0; g < 4; ++g) {
            float4 lv = *(const float4*)&lrX[qh * 32 + 8 * g + 4 * hi];
            invv[g * 4 + 0] = 1.0f / lv.x;
            invv[g * 4 + 1] = 1.0f / lv.y;
            invv[g * 4 + 2] = 1.0f / lv.z;
            invv[g * 4 + 3] = 1.0f / lv.w;
        }
        #pragma unroll
        for (int r16 = 0; r16 < 16; ++r16) {
            const int q = qw + (r16 & 3) + 8 * (r16 >> 2) + 4 * hi;
            u16* zp = &Zb[(((size_t)b * SS + q) * HH + h) * DH_];
            zp[c32]      = f2bf(o0[r16] * invv[r16]);
            zp[32 + c32] = f2bf(o1[r16] * invv[r16]);
        }
    }
}

// ---------------------------------------------------------------------------
extern "C" void kernel_launch(void* const* d_in, const int* in_sizes, int n_in,
                              void* d_out, int out_size, void* d_ws, size_t ws_size,
                              hipStream_t stream) {
    const float* x  = (const float*)d_in[0];
    const float* wq = (const float*)d_in[1];
    const float* wk = (const float*)d_in[2];
    const float* wv = (const float*)d_in[3];
    const float* wo = (const float*)d_in[4];
    const float* bq = (const float*)d_in[5];
    const float* bk = (const float*)d_in[6];
    const float* bv = (const float*)d_in[7];
    const float* bO = (const float*)d_in[8];
    float* out = (float*)d_out;

    char* w = (char*)d_ws;
    u16* Xb  = (u16*)w;  w += (size_t)NROW * DM_ * 2;
    u16* Wt  = (u16*)w;  w += (size_t)NQKV * DM_ * 2;
    u16* WoT = (u16*)w;  w += (size_t)DM_ * DM_ * 2;
    float* biasQKV = (float*)w; w += (size_t)NQKV * 4;
    u16* Qs  = (u16*)w;  w += (size_t)BB * HH * SS * DH_ * 2;
    u16* Ks  = (u16*)w;  w += (size_t)BB * HH * SS * DH_ * 2;
    u16* Vt  = (u16*)w;  w += (size_t)BB * HH * SS * DH_ * 2;
    u16* Zb  = (u16*)w;  w += (size_t)BB * HH * SS * DH_ * 2;

    prep<<<1536, 256, 0, stream>>>(x, wq, wk, wv, wo, bq, bk, bv,
                                   Xb, Wt, WoT, biasQKV);
    gemm_qkv3<<<768, 512, 0, stream>>>(Xb, Wt, biasQKV, Qs, Ks, Vt);
    attn_fwd<<<512, 512, 0, stream>>>(Qs, Ks, Vt, Zb);
    gemm_out3<<<256, 512, 0, stream>>>(Zb, WoT, bO, out);
}